// Round 2
// baseline (392.715 us; speedup 1.0000x reference)
//
#include <hip/hip_runtime.h>
#include <hip/hip_bf16.h>

// HybridEstimator: 3-layer tanh MLP (f16 MFMA) + quantum closed-form epilogue + matvec.
// Inputs (f32): x[8192,1024], W1[1024,2048], b1, W2[2048,2048], b2, W3, b3,
//               Wout[2048,1], bout, weight, bias, scale, shift. Output: f32 [8192].

typedef _Float16 f16;
typedef __attribute__((ext_vector_type(8))) _Float16 f16x8;
typedef __attribute__((ext_vector_type(4))) _Float16 f16x4;
typedef __attribute__((ext_vector_type(4))) float f32x4;

#define BATCH 8192
#define IN_DIM 1024
#define HID 2048

__device__ __forceinline__ float fast_tanh(float x) {
  x = fminf(12.0f, fmaxf(-12.0f, x));
  float e = __expf(2.0f * x);                      // v_exp-based fast exp
  return (e - 1.0f) * __builtin_amdgcn_rcpf(e + 1.0f);
}

// ---- cast f32 -> f16, 4 elems/thread -------------------------------------
__global__ __launch_bounds__(256) void cast_kernel(const float* __restrict__ in,
                                                   f16* __restrict__ out, int n4) {
  int i = blockIdx.x * blockDim.x + threadIdx.x;
  if (i < n4) {
    float4 v = reinterpret_cast<const float4*>(in)[i];
    f16x4 o = { (f16)v.x, (f16)v.y, (f16)v.z, (f16)v.w };
    reinterpret_cast<f16x4*>(out)[i] = o;
  }
}

// ---- transpose + cast: W[K][N] f32 -> Wt[N][K] f16 -----------------------
__global__ __launch_bounds__(256) void transpose_cast_kernel(const float* __restrict__ W,
                                                             f16* __restrict__ Wt,
                                                             int K, int N) {
  __shared__ float tile[32][33];                   // +1 pad: no bank conflicts
  int kb = blockIdx.y * 32, nb = blockIdx.x * 32;
  int tx = threadIdx.x, ty = threadIdx.y;          // 32 x 8
#pragma unroll
  for (int i = 0; i < 4; ++i)
    tile[ty + i * 8][tx] = W[(size_t)(kb + ty + i * 8) * N + nb + tx];
  __syncthreads();
#pragma unroll
  for (int i = 0; i < 4; ++i)
    Wt[(size_t)(nb + ty + i * 8) * K + kb + tx] = (f16)tile[tx][ty + i * 8];
}

// ---- GEMM: Out[M,N] = tanh(A[M,K] * Bt[N,K]^T + bias), f16 in/out --------
// m97 structure: 128x128 tile, BK=64, 4 waves (2x2), 4x4 16x16x32 frags/wave,
// global_load_lds width-16 staging, single-buffered 2-barrier K loop.
#define GLDS16(g, l)                                                         \
  __builtin_amdgcn_global_load_lds(                                          \
      (const __attribute__((address_space(1))) unsigned int*)(g),            \
      (__attribute__((address_space(3))) unsigned int*)(l), 16, 0, 0)

__global__ __launch_bounds__(256) void gemm_bias_tanh(
    const f16* __restrict__ A,    // [8192 x K]
    const f16* __restrict__ Bt,   // [2048 x K]  (W transposed)
    const float* __restrict__ bias,  // [2048] f32
    f16* __restrict__ Out,        // [8192 x 2048]
    int K) {
  __shared__ f16 As[128 * 64];
  __shared__ f16 Bs[128 * 64];

  const int t = threadIdx.x;
  const int l = t & 63;
  const int w = t >> 6;
  const int wr = w >> 1, wc = w & 1;        // wave -> 64x64 quadrant
  const int bm = (int)blockIdx.x >> 4;      // M/128 = 64 row tiles
  const int bn = (int)blockIdx.x & 15;      // N/128 = 16 col tiles
  const int tm = bm << 7, tn = bn << 7;

  const int lr = l & 15;                    // fragment row/col within 16
  const int lk = (l >> 4) << 3;             // k sub-offset: 0,8,16,24

  // staging: thread t moves one 16B chunk per round; 4 rounds per operand
  const int se = t * 8;                     // element offset (round 0)
  const int sm = se >> 6;                   // tile row (rounds add 32 rows)
  const int sk = se & 63;
  const int wbase = w * 512;                // wave-uniform LDS chunk base (elems)

  f32x4 acc[4][4] = {};

  for (int k0 = 0; k0 < K; k0 += 64) {
    const f16* ga = A  + (size_t)(tm + sm) * K + k0 + sk;
    const f16* gb = Bt + (size_t)(tn + sm) * K + k0 + sk;
#pragma unroll
    for (int r = 0; r < 4; ++r)
      GLDS16(ga + (size_t)(r * 32) * K, &As[r * 2048 + wbase]);
#pragma unroll
    for (int r = 0; r < 4; ++r)
      GLDS16(gb + (size_t)(r * 32) * K, &Bs[r * 2048 + wbase]);
    __syncthreads();

#pragma unroll
    for (int ks = 0; ks < 2; ++ks) {
      f16x8 af[4], bf[4];
#pragma unroll
      for (int mi = 0; mi < 4; ++mi)
        af[mi] = *reinterpret_cast<const f16x8*>(
            &As[(wr * 64 + mi * 16 + lr) * 64 + ks * 32 + lk]);
#pragma unroll
      for (int ni = 0; ni < 4; ++ni)
        bf[ni] = *reinterpret_cast<const f16x8*>(
            &Bs[(wc * 64 + ni * 16 + lr) * 64 + ks * 32 + lk]);
#pragma unroll
      for (int mi = 0; mi < 4; ++mi)
#pragma unroll
        for (int ni = 0; ni < 4; ++ni)
          acc[mi][ni] = __builtin_amdgcn_mfma_f32_16x16x32_f16(
              af[mi], bf[ni], acc[mi][ni], 0, 0, 0);
    }
    __syncthreads();
  }

  // epilogue: bias + tanh, store f16. D frag: col=lane&15, row=(lane>>4)*4+j
#pragma unroll
  for (int ni = 0; ni < 4; ++ni) {
    int col = tn + wc * 64 + ni * 16 + lr;
    float bv = bias[col];
#pragma unroll
    for (int mi = 0; mi < 4; ++mi) {
      int row0 = tm + wr * 64 + mi * 16 + ((l >> 4) << 2);
#pragma unroll
      for (int j = 0; j < 4; ++j) {
        float v = fast_tanh(acc[mi][ni][j] + bv);
        Out[(size_t)(row0 + j) * HID + col] = (f16)v;
      }
    }
  }
}

// ---- final: out[b] = sum_n s(core[b,n]) * Wout[n] + bout -----------------
// s(c) = c + (sin(weight)*sin(c) + qbias) * qscale + qshift
__global__ __launch_bounds__(256) void final_reduce(
    const f16* __restrict__ core, const float* __restrict__ Wout,
    const float* __restrict__ bout, const float* __restrict__ weight,
    const float* __restrict__ qbias, const float* __restrict__ qscale,
    const float* __restrict__ qshift, float* __restrict__ out) {
  const int b = blockIdx.x, t = threadIdx.x;
  const float sw = __sinf(weight[0]);
  const float qb = qbias[0], qs = qscale[0], qsh = qshift[0];
  f16x8 c8 = *reinterpret_cast<const f16x8*>(&core[(size_t)b * HID + t * 8]);
  float sum = 0.f;
#pragma unroll
  for (int j = 0; j < 8; ++j) {
    float c = (float)c8[j];
    float s = c + (sw * __sinf(c) + qb) * qs + qsh;
    sum += s * Wout[t * 8 + j];
  }
#pragma unroll
  for (int off = 32; off >= 1; off >>= 1) sum += __shfl_down(sum, off, 64);
  __shared__ float red[4];
  if ((t & 63) == 0) red[t >> 6] = sum;
  __syncthreads();
  if (t == 0) out[b] = red[0] + red[1] + red[2] + red[3] + bout[0];
}

extern "C" void kernel_launch(void* const* d_in, const int* in_sizes, int n_in,
                              void* d_out, int out_size, void* d_ws, size_t ws_size,
                              hipStream_t stream) {
  const float* x    = (const float*)d_in[0];
  const float* W1   = (const float*)d_in[1];
  const float* b1   = (const float*)d_in[2];
  const float* W2   = (const float*)d_in[3];
  const float* b2   = (const float*)d_in[4];
  const float* W3   = (const float*)d_in[5];
  const float* b3   = (const float*)d_in[6];
  const float* Wout = (const float*)d_in[7];
  const float* bout = (const float*)d_in[8];
  const float* wgt  = (const float*)d_in[9];
  const float* qb   = (const float*)d_in[10];
  const float* qs   = (const float*)d_in[11];
  const float* qsh  = (const float*)d_in[12];
  float* out = (float*)d_out;

  char* ws = (char*)d_ws;
  size_t off = 0;
  f16* xh  = (f16*)(ws + off); off += (size_t)BATCH * IN_DIM * sizeof(f16); // 16MB
  f16* w1t = (f16*)(ws + off); off += (size_t)HID * IN_DIM * sizeof(f16);   // 4MB
  f16* w2t = (f16*)(ws + off); off += (size_t)HID * HID * sizeof(f16);      // 8MB
  f16* w3t = (f16*)(ws + off); off += (size_t)HID * HID * sizeof(f16);      // 8MB
  f16* h1  = (f16*)(ws + off); off += (size_t)BATCH * HID * sizeof(f16);    // 32MB
  f16* h2  = (f16*)(ws + off); off += (size_t)BATCH * HID * sizeof(f16);    // 32MB
  // total ~105MB; h1 reused for core_out

  // 1) cast x -> f16
  {
    int n4 = BATCH * IN_DIM / 4;
    cast_kernel<<<(n4 + 255) / 256, 256, 0, stream>>>(x, xh, n4);
  }
  // 2) transpose+cast weights to [N][K] f16
  {
    dim3 blk(32, 8);
    transpose_cast_kernel<<<dim3(HID / 32, IN_DIM / 32), blk, 0, stream>>>(W1, w1t, IN_DIM, HID);
    transpose_cast_kernel<<<dim3(HID / 32, HID / 32),    blk, 0, stream>>>(W2, w2t, HID, HID);
    transpose_cast_kernel<<<dim3(HID / 32, HID / 32),    blk, 0, stream>>>(W3, w3t, HID, HID);
  }
  // 3) three GEMM + bias + tanh layers
  const int grid = (BATCH / 128) * (HID / 128);  // 64*16 = 1024 blocks
  gemm_bias_tanh<<<grid, 256, 0, stream>>>(xh, w1t, b1, h1, IN_DIM);
  gemm_bias_tanh<<<grid, 256, 0, stream>>>(h1, w2t, b2, h2, HID);
  gemm_bias_tanh<<<grid, 256, 0, stream>>>(h2, w3t, b3, h1, HID);
  // 4) quantum epilogue + Wout reduction
  final_reduce<<<BATCH, 256, 0, stream>>>(h1, Wout, bout, wgt, qb, qs, qsh, out);
}

// Round 4
// 362.212 us; speedup vs baseline: 1.0842x; 1.0842x over previous
//
#include <hip/hip_runtime.h>
#include <hip/hip_bf16.h>

// HybridEstimator: 3-layer tanh MLP (f16 MFMA) + quantum closed-form epilogue + matvec.
// Round 3: 256x256-tile 8-wave deep-pipelined GEMM (T2 swizzled LDS + T3/T4
// counted-vmcnt 2-phase schedule + T5 setprio), 4-deep BK=32 circular buffer.

typedef _Float16 f16;
typedef __attribute__((ext_vector_type(8))) _Float16 f16x8;
typedef __attribute__((ext_vector_type(4))) _Float16 f16x4;
typedef __attribute__((ext_vector_type(4))) float f32x4;

#define BATCH 8192
#define IN_DIM 1024
#define HID 2048

__device__ __forceinline__ float fast_tanh(float x) {
  x = fminf(12.0f, fmaxf(-12.0f, x));
  float e = __expf(2.0f * x);
  return (e - 1.0f) * __builtin_amdgcn_rcpf(e + 1.0f);
}

// ---- cast f32 -> f16 ------------------------------------------------------
__global__ __launch_bounds__(256) void cast_kernel(const float* __restrict__ in,
                                                   f16* __restrict__ out, int n4) {
  int i = blockIdx.x * blockDim.x + threadIdx.x;
  if (i < n4) {
    float4 v = reinterpret_cast<const float4*>(in)[i];
    f16x4 o = { (f16)v.x, (f16)v.y, (f16)v.z, (f16)v.w };
    reinterpret_cast<f16x4*>(out)[i] = o;
  }
}

// ---- transpose + cast: W[K][N] f32 -> Wt[N][K] f16 -----------------------
__global__ __launch_bounds__(256) void transpose_cast_kernel(const float* __restrict__ W,
                                                             f16* __restrict__ Wt,
                                                             int K, int N) {
  __shared__ float tile[32][33];
  int kb = blockIdx.y * 32, nb = blockIdx.x * 32;
  int tx = threadIdx.x, ty = threadIdx.y;  // 32 x 8
#pragma unroll
  for (int i = 0; i < 4; ++i)
    tile[ty + i * 8][tx] = W[(size_t)(kb + ty + i * 8) * N + nb + tx];
  __syncthreads();
#pragma unroll
  for (int i = 0; i < 4; ++i)
    Wt[(size_t)(nb + ty + i * 8) * K + kb + tx] = (f16)tile[tx][ty + i * 8];
}

// ---- deep-pipelined 256x256 GEMM + bias + tanh ---------------------------
// Out[M,N] = tanh(A[M,K] * Bt[N,K]^T + bias). 512 thr = 8 waves (2M x 4N),
// per-wave 128x64 C (acc[8][4] of 16x16 frags). K-tiles of 32; 4-deep LDS
// circular buffer (As/Bs[4][8192] f16 = 128 KiB). Stage K-tile t+2 during
// group t (its buffer's readers finished at group t-2 => hazard-free).
// Gates: vmcnt(4) at each group end => previous group's stages (K-tile t+1)
// have landed; never drains to 0 until the tail.
//
// LDS layout (both-sides swizzle, rule 21): within each 8-row block, chunk-
// major: elem(row,chunk) = ((row>>3)*32 + chunk*8 + (row&7))*8. Frag reads
// (16 lanes, same chunk, rows r0..r0+15) hit 8 distinct 16B slots -> 2-way
// (free). GLDS dest stays linear; the global SOURCE address is permuted.

#define GLDS16(g, l)                                                         \
  __builtin_amdgcn_global_load_lds(                                          \
      (const __attribute__((address_space(1))) unsigned int*)(g),            \
      (__attribute__((address_space(3))) unsigned int*)(l), 16, 0, 0)

template <int K>
__global__ __launch_bounds__(512, 2) void gemm256_bias_tanh(
    const f16* __restrict__ A,      // [8192 x K]
    const f16* __restrict__ Bt,     // [2048 x K]
    const float* __restrict__ bias, // [2048]
    f16* __restrict__ Out) {        // [8192 x 2048]
  constexpr int NT = K / 32;
  __shared__ f16 As[4][8192];
  __shared__ f16 Bs[4][8192];

  const int T = threadIdx.x;
  const int l = T & 63;
  const int w = T >> 6;
  const int wm = w >> 2, wn = w & 3;   // wave grid 2(M) x 4(N)
  const int lr = l & 15;               // frag row
  const int lc = l >> 4;               // k-chunk 0..3 (16B units)

  const int bm = (int)blockIdx.x >> 3; // 32 m-tiles
  const int bn = (int)blockIdx.x & 7;  // 8 n-tiles
  const int tm = bm << 8, tn = bn << 8;

  // staging map: linear LDS chunk i = r*512 + T  ->  global (row, kchunk):
  //   row = (i>>5)*8 + (i&7), kchunk = (i>>3)&3
  const int srow = ((T >> 5) << 3) + (T & 7);
  const int skel = ((T >> 3) & 3) << 3;
  const f16* gA0 = A + (size_t)(tm + srow) * K + skel;
  const f16* gA1 = A + (size_t)(tm + srow + 128) * K + skel;
  const f16* gB0 = Bt + (size_t)(tn + srow) * K + skel;
  const f16* gB1 = Bt + (size_t)(tn + srow + 128) * K + skel;
  const int ldsw0 = w * 512;           // wave-uniform LDS elem base, r=0
  const int ldsw1 = 4096 + w * 512;    // r=1

  // frag read base (elems): elem(row,chunk) = block*256 + chunk*64 + (row&7)*8
  const int abase = (wm * 16 + (lr >> 3)) * 256 + lc * 64 + (lr & 7) * 8;
  const int bbase = (wn * 8 + (lr >> 3)) * 256 + lc * 64 + (lr & 7) * 8;

  f32x4 acc[8][4] = {};

  // ---- prologue: stage K-tiles 0 (buf0) and 1 (buf1) ----
  GLDS16(gA0, &As[0][ldsw0]);
  GLDS16(gA1, &As[0][ldsw1]);
  GLDS16(gB0, &Bs[0][ldsw0]);
  GLDS16(gB1, &Bs[0][ldsw1]);
  GLDS16(gA0 + 32, &As[1][ldsw0]);
  GLDS16(gA1 + 32, &As[1][ldsw1]);
  GLDS16(gB0 + 32, &Bs[1][ldsw0]);
  GLDS16(gB1 + 32, &Bs[1][ldsw1]);
  asm volatile("s_waitcnt vmcnt(4)" ::: "memory");  // K-tile 0 landed
  __builtin_amdgcn_s_barrier();
  __builtin_amdgcn_sched_barrier(0);

  for (int t = 0; t < NT; ++t) {
    const int q = t & 3;
    // ======== phase A: frags a[0..3], b[0..3]; stage A of t+2 ========
    f16x8 afr[4], bfr[4];
#pragma unroll
    for (int mi = 0; mi < 4; ++mi)
      afr[mi] = *reinterpret_cast<const f16x8*>(&As[q][abase + mi * 512]);
#pragma unroll
    for (int ni = 0; ni < 4; ++ni)
      bfr[ni] = *reinterpret_cast<const f16x8*>(&Bs[q][bbase + ni * 512]);
    if (t + 2 < NT) {
      const int q2 = (t + 2) & 3;
      const int ko = (t + 2) * 32;
      GLDS16(gA0 + ko, &As[q2][ldsw0]);
      GLDS16(gA1 + ko, &As[q2][ldsw1]);
    }
    __builtin_amdgcn_s_barrier();
    asm volatile("s_waitcnt lgkmcnt(0)" ::: "memory");
    __builtin_amdgcn_sched_barrier(0);
    __builtin_amdgcn_s_setprio(1);
#pragma unroll
    for (int mi = 0; mi < 4; ++mi)
#pragma unroll
      for (int ni = 0; ni < 4; ++ni)
        acc[mi][ni] = __builtin_amdgcn_mfma_f32_16x16x32_f16(
            afr[mi], bfr[ni], acc[mi][ni], 0, 0, 0);
    __builtin_amdgcn_s_setprio(0);
    __builtin_amdgcn_s_barrier();
    __builtin_amdgcn_sched_barrier(0);

    // ======== phase B: frags a[4..7] (b reused); stage B of t+2; gate ====
    f16x8 afr2[4];
#pragma unroll
    for (int mi = 0; mi < 4; ++mi)
      afr2[mi] = *reinterpret_cast<const f16x8*>(&As[q][abase + (4 + mi) * 512]);
    if (t + 2 < NT) {
      const int q2 = (t + 2) & 3;
      const int ko = (t + 2) * 32;
      GLDS16(gB0 + ko, &Bs[q2][ldsw0]);
      GLDS16(gB1 + ko, &Bs[q2][ldsw1]);
      asm volatile("s_waitcnt vmcnt(4)" ::: "memory");  // K-tile t+1 landed
    } else {
      asm volatile("s_waitcnt vmcnt(0)" ::: "memory");  // tail drain
    }
    __builtin_amdgcn_s_barrier();
    asm volatile("s_waitcnt lgkmcnt(0)" ::: "memory");
    __builtin_amdgcn_sched_barrier(0);
    __builtin_amdgcn_s_setprio(1);
#pragma unroll
    for (int mi = 0; mi < 4; ++mi)
#pragma unroll
      for (int ni = 0; ni < 4; ++ni)
        acc[4 + mi][ni] = __builtin_amdgcn_mfma_f32_16x16x32_f16(
            afr2[mi], bfr[ni], acc[4 + mi][ni], 0, 0, 0);
    __builtin_amdgcn_s_setprio(0);
    __builtin_amdgcn_s_barrier();
    __builtin_amdgcn_sched_barrier(0);
  }

  // ---- epilogue: bias + tanh, f16 store. D: col=lane&15, row=(lane>>4)*4+j
#pragma unroll
  for (int ni = 0; ni < 4; ++ni) {
    const int col = tn + wn * 64 + ni * 16 + lr;
    const float bv = bias[col];
#pragma unroll
    for (int mi = 0; mi < 8; ++mi) {
      const int row0 = tm + wm * 128 + mi * 16 + ((l >> 4) << 2);
#pragma unroll
      for (int j = 0; j < 4; ++j) {
        float v = fast_tanh(acc[mi][ni][j] + bv);
        Out[(size_t)(row0 + j) * HID + col] = (f16)v;
      }
    }
  }
}

// ---- final: out[b] = sum_n s(core[b,n]) * Wout[n] + bout -----------------
__global__ __launch_bounds__(256) void final_reduce(
    const f16* __restrict__ core, const float* __restrict__ Wout,
    const float* __restrict__ bout, const float* __restrict__ weight,
    const float* __restrict__ qbias, const float* __restrict__ qscale,
    const float* __restrict__ qshift, float* __restrict__ out) {
  const int b = blockIdx.x, t = threadIdx.x;
  const float sw = __sinf(weight[0]);
  const float qb = qbias[0], qs = qscale[0], qsh = qshift[0];
  f16x8 c8 = *reinterpret_cast<const f16x8*>(&core[(size_t)b * HID + t * 8]);
  float sum = 0.f;
#pragma unroll
  for (int j = 0; j < 8; ++j) {
    float c = (float)c8[j];
    float s = c + (sw * __sinf(c) + qb) * qs + qsh;
    sum += s * Wout[t * 8 + j];
  }
#pragma unroll
  for (int off = 32; off >= 1; off >>= 1) sum += __shfl_down(sum, off, 64);
  __shared__ float red[4];
  if ((t & 63) == 0) red[t >> 6] = sum;
  __syncthreads();
  if (t == 0) out[b] = red[0] + red[1] + red[2] + red[3] + bout[0];
}

extern "C" void kernel_launch(void* const* d_in, const int* in_sizes, int n_in,
                              void* d_out, int out_size, void* d_ws, size_t ws_size,
                              hipStream_t stream) {
  const float* x    = (const float*)d_in[0];
  const float* W1   = (const float*)d_in[1];
  const float* b1   = (const float*)d_in[2];
  const float* W2   = (const float*)d_in[3];
  const float* b2   = (const float*)d_in[4];
  const float* W3   = (const float*)d_in[5];
  const float* b3   = (const float*)d_in[6];
  const float* Wout = (const float*)d_in[7];
  const float* bout = (const float*)d_in[8];
  const float* wgt  = (const float*)d_in[9];
  const float* qb   = (const float*)d_in[10];
  const float* qs   = (const float*)d_in[11];
  const float* qsh  = (const float*)d_in[12];
  float* out = (float*)d_out;

  char* ws = (char*)d_ws;
  size_t off = 0;
  f16* xh  = (f16*)(ws + off); off += (size_t)BATCH * IN_DIM * sizeof(f16);
  f16* w1t = (f16*)(ws + off); off += (size_t)HID * IN_DIM * sizeof(f16);
  f16* w2t = (f16*)(ws + off); off += (size_t)HID * HID * sizeof(f16);
  f16* w3t = (f16*)(ws + off); off += (size_t)HID * HID * sizeof(f16);
  f16* h1  = (f16*)(ws + off); off += (size_t)BATCH * HID * sizeof(f16);
  f16* h2  = (f16*)(ws + off); off += (size_t)BATCH * HID * sizeof(f16);

  {
    int n4 = BATCH * IN_DIM / 4;
    cast_kernel<<<(n4 + 255) / 256, 256, 0, stream>>>(x, xh, n4);
  }
  {
    dim3 blk(32, 8);
    transpose_cast_kernel<<<dim3(HID / 32, IN_DIM / 32), blk, 0, stream>>>(W1, w1t, IN_DIM, HID);
    transpose_cast_kernel<<<dim3(HID / 32, HID / 32),    blk, 0, stream>>>(W2, w2t, HID, HID);
    transpose_cast_kernel<<<dim3(HID / 32, HID / 32),    blk, 0, stream>>>(W3, w3t, HID, HID);
  }
  const int grid = (BATCH / 256) * (HID / 256);  // 32*8 = 256 blocks = 1/CU
  gemm256_bias_tanh<IN_DIM><<<grid, 512, 0, stream>>>(xh, w1t, b1, h1);
  gemm256_bias_tanh<HID>   <<<grid, 512, 0, stream>>>(h1, w2t, b2, h2);
  gemm256_bias_tanh<HID>   <<<grid, 512, 0, stream>>>(h2, w3t, b3, h1);
  final_reduce<<<BATCH, 256, 0, stream>>>(h1, Wout, bout, wgt, qb, qs, qsh, out);
}

// Round 5
// 332.563 us; speedup vs baseline: 1.1809x; 1.0892x over previous
//
#include <hip/hip_runtime.h>
#include <hip/hip_bf16.h>

// HybridEstimator: 3-layer tanh MLP (f16 MFMA) + quantum closed-form epilogue + matvec.
// Round 5: single-phase-per-K-tile loop (compiler-scheduled ds_reads, 32 MFMA /
// barrier), 4-deep circular LDS buffer staged t+3 ahead with vmcnt(8) gates,
// coalesced LDS-bounce epilogue, fused weight-transpose launch.

typedef _Float16 f16;
typedef __attribute__((ext_vector_type(8))) _Float16 f16x8;
typedef __attribute__((ext_vector_type(4))) _Float16 f16x4;
typedef __attribute__((ext_vector_type(4))) float f32x4;

#define BATCH 8192
#define IN_DIM 1024
#define HID 2048

__device__ __forceinline__ float fast_tanh(float x) {
  x = fminf(12.0f, fmaxf(-12.0f, x));
  float e = __expf(2.0f * x);
  return (e - 1.0f) * __builtin_amdgcn_rcpf(e + 1.0f);
}

// ---- cast f32 -> f16 ------------------------------------------------------
__global__ __launch_bounds__(256) void cast_kernel(const float* __restrict__ in,
                                                   f16* __restrict__ out, int n4) {
  int i = blockIdx.x * blockDim.x + threadIdx.x;
  if (i < n4) {
    float4 v = reinterpret_cast<const float4*>(in)[i];
    f16x4 o = { (f16)v.x, (f16)v.y, (f16)v.z, (f16)v.w };
    reinterpret_cast<f16x4*>(out)[i] = o;
  }
}

// ---- fused transpose+cast for all 3 weights: W[K][N] f32 -> Wt[N][K] f16 --
__global__ __launch_bounds__(256) void transpose_cast3(
    const float* __restrict__ W1, const float* __restrict__ W2,
    const float* __restrict__ W3, f16* __restrict__ w1t,
    f16* __restrict__ w2t, f16* __restrict__ w3t) {
  __shared__ float tile[32][33];
  int b = blockIdx.x;
  const float* W; f16* Wt; int K, N;
  if (b < 2048)      { W = W1; Wt = w1t; K = IN_DIM; N = HID; }
  else if (b < 6144) { W = W2; Wt = w2t; K = HID;    N = HID; b -= 2048; }
  else               { W = W3; Wt = w3t; K = HID;    N = HID; b -= 6144; }
  const int nbt = N / 32;
  const int nb = (b % nbt) * 32, kb = (b / nbt) * 32;
  const int tx = threadIdx.x, ty = threadIdx.y;  // 32 x 8
#pragma unroll
  for (int i = 0; i < 4; ++i)
    tile[ty + i * 8][tx] = W[(size_t)(kb + ty + i * 8) * N + nb + tx];
  __syncthreads();
#pragma unroll
  for (int i = 0; i < 4; ++i)
    Wt[(size_t)(nb + ty + i * 8) * K + kb + tx] = (f16)tile[tx][ty + i * 8];
}

// ---- 256x256 GEMM + bias + tanh, deep pipeline ---------------------------
// Out = tanh(A[M,K] * Bt[N,K]^T + bias). 512 thr = 8 waves (2M x 4N), per-wave
// 128x64 C = acc[8][4]. BK=32, 4-deep circular LDS buffer (128 KiB). Per
// K-tile: 12 ds_read_b128 + stage tile t+3 (4 GLDS) + 32 MFMA + vmcnt(8) gate
// + ONE barrier. Compiler inserts fine-grained lgkm waits (no explicit drain).
// Hazards: buf (t+3)&3 last read at group t-1 (reads complete before its
// ending barrier) => write at group t safe. Gate at group t end leaves tiles
// t+2,t+3 (8 loads) in flight => tile t+1 landed before its reads at t+1.
// LDS layout (both-sides swizzle): chunk-major within 8-row blocks:
// elem(row,kchunk) = ((row>>3)*32 + kchunk*8 + (row&7))*8; GLDS dest linear,
// global source pre-permuted; frag reads conflict-free (measured 0 in r4).

#define GLDS16(g, l)                                                         \
  __builtin_amdgcn_global_load_lds(                                          \
      (const __attribute__((address_space(1))) unsigned int*)(g),            \
      (__attribute__((address_space(3))) unsigned int*)(l), 16, 0, 0)

template <int K>
__global__ __launch_bounds__(512, 2) void gemm256_bias_tanh(
    const f16* __restrict__ A,      // [8192 x K]
    const f16* __restrict__ Bt,     // [2048 x K]
    const float* __restrict__ bias, // [2048]
    f16* __restrict__ Out) {        // [8192 x 2048]
  constexpr int NT = K / 32;
  __shared__ f16 smem[65536];       // 128 KiB: As = [0,32768), Bs = [32768,65536)
  f16* As = smem;
  f16* Bs = smem + 32768;

  const int T = threadIdx.x;
  const int l = T & 63;
  const int w = T >> 6;
  const int wm = w >> 2, wn = w & 3;   // wave grid 2(M) x 4(N)
  const int lr = l & 15;               // frag row
  const int lc = l >> 4;               // k-chunk 0..3

  const int bm = (int)blockIdx.x >> 3; // 32 m-tiles
  const int bn = (int)blockIdx.x & 7;  // 8 n-tiles
  const int tm = bm << 8, tn = bn << 8;

  // staging source map (pre-swizzled): chunk i = T -> row=(T>>5)*8+(T&7),
  // kchunk=(T>>3)&3
  const int srow = ((T >> 5) << 3) + (T & 7);
  const int skel = ((T >> 3) & 3) << 3;
  const f16* gA0 = A + (size_t)(tm + srow) * K + skel;
  const f16* gA1 = A + (size_t)(tm + srow + 128) * K + skel;
  const f16* gB0 = Bt + (size_t)(tn + srow) * K + skel;
  const f16* gB1 = Bt + (size_t)(tn + srow + 128) * K + skel;
  const int ldsw0 = w * 512;           // wave-uniform LDS elem base, half 0
  const int ldsw1 = 4096 + w * 512;    // half 1

  // frag read base: elem(row,kchunk) = rowgrp*256 + kchunk*64 + (row&7)*8
  const int abase = (wm * 16 + (lr >> 3)) * 256 + lc * 64 + (lr & 7) * 8;
  const int bbase = (wn * 8 + (lr >> 3)) * 256 + lc * 64 + (lr & 7) * 8;

  f32x4 acc[8][4] = {};

  // ---- prologue: stage K-tiles 0,1,2 (12 loads); oldest 4 = tile 0 ----
#pragma unroll
  for (int p = 0; p < 3; ++p) {
    const int ko = p * 32;
    f16* aq = As + p * 8192;
    f16* bq = Bs + p * 8192;
    GLDS16(gA0 + ko, aq + ldsw0);
    GLDS16(gA1 + ko, aq + ldsw1);
    GLDS16(gB0 + ko, bq + ldsw0);
    GLDS16(gB1 + ko, bq + ldsw1);
  }
  asm volatile("s_waitcnt vmcnt(8)" ::: "memory");  // tile 0 landed
  __builtin_amdgcn_s_barrier();
  __builtin_amdgcn_sched_barrier(0);

  for (int t = 0; t < NT; ++t) {
    const int q = t & 3;
    const f16* aq = As + q * 8192;
    const f16* bq = Bs + q * 8192;
    f16x8 afr[8], bfr[4];
#pragma unroll
    for (int mi = 0; mi < 8; ++mi)
      afr[mi] = *reinterpret_cast<const f16x8*>(&aq[abase + mi * 512]);
#pragma unroll
    for (int ni = 0; ni < 4; ++ni)
      bfr[ni] = *reinterpret_cast<const f16x8*>(&bq[bbase + ni * 512]);
    if (t + 3 < NT) {                  // stage K-tile t+3
      const int q3 = (t + 3) & 3;
      const int ko = (t + 3) * 32;
      f16* aw = As + q3 * 8192;
      f16* bw = Bs + q3 * 8192;
      GLDS16(gA0 + ko, aw + ldsw0);
      GLDS16(gA1 + ko, aw + ldsw1);
      GLDS16(gB0 + ko, bw + ldsw0);
      GLDS16(gB1 + ko, bw + ldsw1);
    }
    __builtin_amdgcn_s_setprio(1);
#pragma unroll
    for (int mi = 0; mi < 8; ++mi)
#pragma unroll
      for (int ni = 0; ni < 4; ++ni)
        acc[mi][ni] = __builtin_amdgcn_mfma_f32_16x16x32_f16(
            afr[mi], bfr[ni], acc[mi][ni], 0, 0, 0);
    __builtin_amdgcn_s_setprio(0);
    if (t + 3 < NT) {
      asm volatile("s_waitcnt vmcnt(8)" ::: "memory");  // tile t+1 landed
    } else if (t + 2 < NT) {
      asm volatile("s_waitcnt vmcnt(4)" ::: "memory");  // t = NT-3
    } else {
      asm volatile("s_waitcnt vmcnt(0)" ::: "memory");  // tail drain
    }
    __builtin_amdgcn_s_barrier();
    __builtin_amdgcn_sched_barrier(0);
  }

  // ---- epilogue: bias+tanh -> LDS bounce (XOR swizzle) -> coalesced store
  // D frag: col=lane&15, row=(lane>>4)*4+j. LDS byte(r,c)=r*512+((c*2)^((r&7)<<4))
#pragma unroll
  for (int ni = 0; ni < 4; ++ni) {
    const int col = wn * 64 + ni * 16 + lr;
    const float bv = bias[tn + col];
#pragma unroll
    for (int mi = 0; mi < 8; ++mi) {
      const int r0 = wm * 128 + mi * 16 + ((l >> 4) << 2);
#pragma unroll
      for (int j = 0; j < 4; ++j) {
        const int r = r0 + j;
        const int bo = r * 512 + ((col * 2) ^ ((r & 7) << 4));
        *reinterpret_cast<f16*>(reinterpret_cast<char*>(smem) + bo) =
            (f16)fast_tanh(acc[mi][ni][j] + bv);
      }
    }
  }
  __syncthreads();
  // copy out: wave w -> rows [w*32, w*32+32), 2 rows per iter, dwordx4 stores
#pragma unroll
  for (int it = 0; it < 16; ++it) {
    const int r = w * 32 + it * 2 + (l >> 5);
    const int cb = (l & 31) * 16;      // byte col within 512B row
    const int so = r * 512 + (cb ^ ((r & 7) << 4));
    f16x8 v = *reinterpret_cast<const f16x8*>(
        reinterpret_cast<const char*>(smem) + so);
    *reinterpret_cast<f16x8*>(
        reinterpret_cast<char*>(Out + (size_t)(tm + r) * HID + tn) + cb) = v;
  }
}

// ---- final: out[b] = sum_n s(core[b,n]) * Wout[n] + bout -----------------
__global__ __launch_bounds__(256) void final_reduce(
    const f16* __restrict__ core, const float* __restrict__ Wout,
    const float* __restrict__ bout, const float* __restrict__ weight,
    const float* __restrict__ qbias, const float* __restrict__ qscale,
    const float* __restrict__ qshift, float* __restrict__ out) {
  const int b = blockIdx.x, t = threadIdx.x;
  const float sw = __sinf(weight[0]);
  const float qb = qbias[0], qs = qscale[0], qsh = qshift[0];
  f16x8 c8 = *reinterpret_cast<const f16x8*>(&core[(size_t)b * HID + t * 8]);
  float sum = 0.f;
#pragma unroll
  for (int j = 0; j < 8; ++j) {
    float c = (float)c8[j];
    float s = c + (sw * __sinf(c) + qb) * qs + qsh;
    sum += s * Wout[t * 8 + j];
  }
#pragma unroll
  for (int off = 32; off >= 1; off >>= 1) sum += __shfl_down(sum, off, 64);
  __shared__ float red[4];
  if ((t & 63) == 0) red[t >> 6] = sum;
  __syncthreads();
  if (t == 0) out[b] = red[0] + red[1] + red[2] + red[3] + bout[0];
}

extern "C" void kernel_launch(void* const* d_in, const int* in_sizes, int n_in,
                              void* d_out, int out_size, void* d_ws, size_t ws_size,
                              hipStream_t stream) {
  const float* x    = (const float*)d_in[0];
  const float* W1   = (const float*)d_in[1];
  const float* b1   = (const float*)d_in[2];
  const float* W2   = (const float*)d_in[3];
  const float* b2   = (const float*)d_in[4];
  const float* W3   = (const float*)d_in[5];
  const float* b3   = (const float*)d_in[6];
  const float* Wout = (const float*)d_in[7];
  const float* bout = (const float*)d_in[8];
  const float* wgt  = (const float*)d_in[9];
  const float* qb   = (const float*)d_in[10];
  const float* qs   = (const float*)d_in[11];
  const float* qsh  = (const float*)d_in[12];
  float* out = (float*)d_out;

  char* ws = (char*)d_ws;
  size_t off = 0;
  f16* xh  = (f16*)(ws + off); off += (size_t)BATCH * IN_DIM * sizeof(f16);
  f16* w1t = (f16*)(ws + off); off += (size_t)HID * IN_DIM * sizeof(f16);
  f16* w2t = (f16*)(ws + off); off += (size_t)HID * HID * sizeof(f16);
  f16* w3t = (f16*)(ws + off); off += (size_t)HID * HID * sizeof(f16);
  f16* h1  = (f16*)(ws + off); off += (size_t)BATCH * HID * sizeof(f16);
  f16* h2  = (f16*)(ws + off); off += (size_t)BATCH * HID * sizeof(f16);

  {
    int n4 = BATCH * IN_DIM / 4;
    cast_kernel<<<(n4 + 255) / 256, 256, 0, stream>>>(x, xh, n4);
  }
  {
    dim3 blk(32, 8);
    transpose_cast3<<<10240, blk, 0, stream>>>(W1, W2, W3, w1t, w2t, w3t);
  }
  const int grid = (BATCH / 256) * (HID / 256);  // 256 blocks = 1/CU
  gemm256_bias_tanh<IN_DIM><<<grid, 512, 0, stream>>>(xh, w1t, b1, h1);
  gemm256_bias_tanh<HID>   <<<grid, 512, 0, stream>>>(h1, w2t, b2, h2);
  gemm256_bias_tanh<HID>   <<<grid, 512, 0, stream>>>(h2, w3t, b3, h1);
  final_reduce<<<BATCH, 256, 0, stream>>>(h1, Wout, bout, wgt, qb, qs, qsh, out);
}

// Round 8
// 328.272 us; speedup vs baseline: 1.1963x; 1.0131x over previous
//
#include <hip/hip_runtime.h>
#include <hip/hip_bf16.h>

// HybridEstimator: 3-layer tanh MLP (f16 MFMA) + quantum epilogue + matvec.
// Round 6: true 8-phase schedule (m201 template): BK=64, 4 phases/K-tile,
// 16 MFMA/phase between barrier pairs, 4/8 ds_reads/phase, collective GLDS
// staging with counted vmcnt(4) gates before barriers (never 0 until tail).

typedef _Float16 f16;
typedef __attribute__((ext_vector_type(8))) _Float16 f16x8;
typedef __attribute__((ext_vector_type(4))) _Float16 f16x4;
typedef __attribute__((ext_vector_type(4))) float f32x4;

#define BATCH 8192
#define IN_DIM 1024
#define HID 2048

__device__ __forceinline__ float fast_tanh(float x) {
  x = fminf(12.0f, fmaxf(-12.0f, x));
  float e = __expf(2.0f * x);
  return (e - 1.0f) * __builtin_amdgcn_rcpf(e + 1.0f);
}

// ---- cast f32 -> f16 ------------------------------------------------------
__global__ __launch_bounds__(256) void cast_kernel(const float* __restrict__ in,
                                                   f16* __restrict__ out, int n4) {
  int i = blockIdx.x * blockDim.x + threadIdx.x;
  if (i < n4) {
    float4 v = reinterpret_cast<const float4*>(in)[i];
    f16x4 o = { (f16)v.x, (f16)v.y, (f16)v.z, (f16)v.w };
    reinterpret_cast<f16x4*>(out)[i] = o;
  }
}

// ---- fused transpose+cast for all 3 weights ------------------------------
__global__ __launch_bounds__(256) void transpose_cast3(
    const float* __restrict__ W1, const float* __restrict__ W2,
    const float* __restrict__ W3, f16* __restrict__ w1t,
    f16* __restrict__ w2t, f16* __restrict__ w3t) {
  __shared__ float tile[32][33];
  int b = blockIdx.x;
  const float* W; f16* Wt; int K, N;
  if (b < 2048)      { W = W1; Wt = w1t; K = IN_DIM; N = HID; }
  else if (b < 6144) { W = W2; Wt = w2t; K = HID;    N = HID; b -= 2048; }
  else               { W = W3; Wt = w3t; K = HID;    N = HID; b -= 6144; }
  const int nbt = N / 32;
  const int nb = (b % nbt) * 32, kb = (b / nbt) * 32;
  const int tx = threadIdx.x, ty = threadIdx.y;  // 32 x 8
#pragma unroll
  for (int i = 0; i < 4; ++i)
    tile[ty + i * 8][tx] = W[(size_t)(kb + ty + i * 8) * N + nb + tx];
  __syncthreads();
#pragma unroll
  for (int i = 0; i < 4; ++i)
    Wt[(size_t)(nb + ty + i * 8) * K + kb + tx] = (f16)tile[tx][ty + i * 8];
}

// ---- 256x256 GEMM + bias + tanh, 8-phase schedule ------------------------
// 512 thr = 8 waves (2M x 4N), per-wave 128x64 C = acc[8][4]. BK=64 tiles,
// NT=K/64. LDS: 2 buffers x 2 k-half subtiles x (A 16KB + B 16KB) = 128 KiB;
// each k-half subtile uses the proven chunk-major conflict-free layout:
// elem(row,kc) = ((row>>3)*32 + kc*8 + (row&7))*8, kc in [0,4).
// Staging: all waves issue the identical STAGE sequence; gates sit BEFORE
// phase-end barriers, so barrier transitively proves all waves' units landed.
// Units per tile: Au0,Bu0,Au1,Bu1 (2 GLDS each/wave), staged for tile t+1 at
// phases P1..P4 of tile t, into buffer (t+1)&1 (never the read buffer).
// Gates: vmcnt(4) at P2-end (proves t's Au1,Bu1) and P4-end (proves t+1's
// Au0,Bu0). Tail: vmcnt(0) at NT-1 P2. Per phase: [4|8 ds_read_b128; 2 GLDS;
// s_barrier; lgkmcnt(0); sched_barrier; setprio(1); 16 MFMA; setprio(0);
// (gate); s_barrier].

#define GLDS16(g, l)                                                         \
  __builtin_amdgcn_global_load_lds(                                          \
      (const __attribute__((address_space(1))) unsigned int*)(g),            \
      (__attribute__((address_space(3))) unsigned int*)(l), 16, 0, 0)

template <int K>
__global__ __launch_bounds__(512, 2) void gemm256_bias_tanh(
    const f16* __restrict__ A,      // [8192 x K]
    const f16* __restrict__ Bt,     // [2048 x K]
    const float* __restrict__ bias, // [2048]
    f16* __restrict__ Out) {        // [8192 x 2048]
  constexpr int NT = K / 64;
  __shared__ f16 smem[65536];       // A: [b*16384 + u*8192), B: +32768

  const int T = threadIdx.x;
  const int l = T & 63;
  const int w = T >> 6;
  const int wm = w >> 2, wn = w & 3;   // wave grid 2(M) x 4(N)
  const int lr = l & 15, lc = l >> 4;

  const int bm = (int)blockIdx.x >> 3; // 32 m-tiles
  const int bn = (int)blockIdx.x & 7;  // 8 n-tiles
  const int tm = bm << 8, tn = bn << 8;

  // frag read bases (elems within a k-half subtile)
  const int abase = (wm * 16 + (lr >> 3)) * 256 + lc * 64 + (lr & 7) * 8;
  const int bbase = (wn * 8 + (lr >> 3)) * 256 + lc * 64 + (lr & 7) * 8;

  // staging maps: chunk-in-half cc -> row=((cc>>5)<<3)|(cc&7), k=((cc>>3)&3)*8
  const int ccA0 = wm * 512 + wn * 128 + l;
  const int ccA1 = ccA0 + 64;
  const int ccB0 = (wn >> 1) * 512 + (wm * 2 + (wn & 1)) * 128 + l;
  const int ccB1 = ccB0 + 64;
#define ROWOF(cc) ((((cc) >> 5) << 3) | ((cc) & 7))
#define KLOF(cc) ((((cc) >> 3) & 3) * 8)
  const f16* pa0 = A + (size_t)(tm + ROWOF(ccA0)) * K + KLOF(ccA0);
  const f16* pa1 = A + (size_t)(tm + ROWOF(ccA1)) * K + KLOF(ccA1);
  const f16* pb0 = Bt + (size_t)(tn + ROWOF(ccB0)) * K + KLOF(ccB0);
  const f16* pb1 = Bt + (size_t)(tn + ROWOF(ccB1)) * K + KLOF(ccB1);
  const int dA = wm * 4096 + wn * 1024;
  const int dB = 32768 + (wn >> 1) * 4096 + (wm * 2 + (wn & 1)) * 1024;

#define STAGE_A(tt, u)                                                       \
  do {                                                                       \
    const int _b = ((tt) & 1) * 16384 + (u) * 8192;                          \
    GLDS16(pa0 + (tt) * 64 + (u) * 32, &smem[_b + dA]);                      \
    GLDS16(pa1 + (tt) * 64 + (u) * 32, &smem[_b + dA + 512]);                \
  } while (0)
#define STAGE_B(tt, u)                                                       \
  do {                                                                       \
    const int _b = ((tt) & 1) * 16384 + (u) * 8192;                          \
    GLDS16(pb0 + (tt) * 64 + (u) * 32, &smem[_b + dB]);                      \
    GLDS16(pb1 + (tt) * 64 + (u) * 32, &smem[_b + dB + 512]);                \
  } while (0)
#define LDF(p) (*reinterpret_cast<const f16x8*>(p))
#define MFMA4(base)                                                          \
  _Pragma("unroll") for (int mi = 0; mi < 4; ++mi)                           \
  _Pragma("unroll") for (int ni = 0; ni < 4; ++ni)                           \
      acc[(base) + mi][ni] = __builtin_amdgcn_mfma_f32_16x16x32_f16(         \
          afr[mi], bfr[ni], acc[(base) + mi][ni], 0, 0, 0);

  f32x4 acc[8][4] = {};

  // ---- prologue: stage tile 0's 4 units ----
  STAGE_A(0, 0); STAGE_B(0, 0); STAGE_A(0, 1); STAGE_B(0, 1);
  asm volatile("s_waitcnt vmcnt(4)" ::: "memory");  // Au0,Bu0 landed
  __builtin_amdgcn_s_barrier();

  for (int t = 0; t < NT; ++t) {
    const int bo = (t & 1) * 16384;
    const f16* As0 = smem + bo;                 // k-half 0
    const f16* As1 = smem + bo + 8192;          // k-half 1
    const f16* Bs0 = smem + 32768 + bo;
    const f16* Bs1 = smem + 32768 + bo + 8192;
    f16x8 afr[4], bfr[4];

    // ===== P1: reads B(ks0) + A(mh0,ks0); stage (t+1).Au0 =====
#pragma unroll
    for (int ni = 0; ni < 4; ++ni) bfr[ni] = LDF(Bs0 + bbase + ni * 512);
#pragma unroll
    for (int mi = 0; mi < 4; ++mi) afr[mi] = LDF(As0 + abase + mi * 512);
    if (t + 1 < NT) STAGE_A(t + 1, 0);
    __builtin_amdgcn_s_barrier();
    asm volatile("s_waitcnt lgkmcnt(0)" ::: "memory");
    __builtin_amdgcn_sched_barrier(0);
    __builtin_amdgcn_s_setprio(1);
    MFMA4(0)
    __builtin_amdgcn_s_setprio(0);
    __builtin_amdgcn_s_barrier();

    // ===== P2: reads A(mh1,ks0); stage (t+1).Bu0; gate vmcnt =====
#pragma unroll
    for (int mi = 0; mi < 4; ++mi) afr[mi] = LDF(As0 + abase + (4 + mi) * 512);
    if (t + 1 < NT) STAGE_B(t + 1, 0);
    __builtin_amdgcn_s_barrier();
    asm volatile("s_waitcnt lgkmcnt(0)" ::: "memory");
    __builtin_amdgcn_sched_barrier(0);
    __builtin_amdgcn_s_setprio(1);
    MFMA4(4)
    __builtin_amdgcn_s_setprio(0);
    if (t + 1 < NT) {
      asm volatile("s_waitcnt vmcnt(4)" ::: "memory");  // Au1(t),Bu1(t) landed
    } else {
      asm volatile("s_waitcnt vmcnt(0)" ::: "memory");  // tail drain
    }
    __builtin_amdgcn_s_barrier();

    // ===== P3: reads B(ks1) + A(mh0,ks1); stage (t+1).Au1 =====
#pragma unroll
    for (int ni = 0; ni < 4; ++ni) bfr[ni] = LDF(Bs1 + bbase + ni * 512);
#pragma unroll
    for (int mi = 0; mi < 4; ++mi) afr[mi] = LDF(As1 + abase + mi * 512);
    if (t + 1 < NT) STAGE_A(t + 1, 1);
    __builtin_amdgcn_s_barrier();
    asm volatile("s_waitcnt lgkmcnt(0)" ::: "memory");
    __builtin_amdgcn_sched_barrier(0);
    __builtin_amdgcn_s_setprio(1);
    MFMA4(0)
    __builtin_amdgcn_s_setprio(0);
    __builtin_amdgcn_s_barrier();

    // ===== P4: reads A(mh1,ks1); stage (t+1).Bu1; gate vmcnt =====
#pragma unroll
    for (int mi = 0; mi < 4; ++mi) afr[mi] = LDF(As1 + abase + (4 + mi) * 512);
    if (t + 1 < NT) STAGE_B(t + 1, 1);
    __builtin_amdgcn_s_barrier();
    asm volatile("s_waitcnt lgkmcnt(0)" ::: "memory");
    __builtin_amdgcn_sched_barrier(0);
    __builtin_amdgcn_s_setprio(1);
    MFMA4(4)
    __builtin_amdgcn_s_setprio(0);
    if (t + 1 < NT) {
      asm volatile("s_waitcnt vmcnt(4)" ::: "memory");  // Au0,Bu0(t+1) landed
    }
    __builtin_amdgcn_s_barrier();
  }

  __syncthreads();  // full fence before reusing LDS as epilogue bounce

  // ---- epilogue: bias+tanh -> LDS bounce (XOR swizzle) -> coalesced store
  // D frag: col=lane&15, row=(lane>>4)*4+j. byte(r,c)=r*512+((c*2)^((r&7)<<4))
#pragma unroll
  for (int ni = 0; ni < 4; ++ni) {
    const int col = wn * 64 + ni * 16 + lr;
    const float bv = bias[tn + col];
#pragma unroll
    for (int mi = 0; mi < 8; ++mi) {
      const int r0 = wm * 128 + mi * 16 + ((l >> 4) << 2);
#pragma unroll
      for (int j = 0; j < 4; ++j) {
        const int r = r0 + j;
        const int bo2 = r * 512 + ((col * 2) ^ ((r & 7) << 4));
        *reinterpret_cast<f16*>(reinterpret_cast<char*>(smem) + bo2) =
            (f16)fast_tanh(acc[mi][ni][j] + bv);
      }
    }
  }
  __syncthreads();
#pragma unroll
  for (int it = 0; it < 16; ++it) {
    const int r = w * 32 + it * 2 + (l >> 5);
    const int cb = (l & 31) * 16;
    const int so = r * 512 + (cb ^ ((r & 7) << 4));
    f16x8 v = *reinterpret_cast<const f16x8*>(
        reinterpret_cast<const char*>(smem) + so);
    *reinterpret_cast<f16x8*>(
        reinterpret_cast<char*>(Out + (size_t)(tm + r) * HID + tn) + cb) = v;
  }
#undef STAGE_A
#undef STAGE_B
#undef LDF
#undef MFMA4
#undef ROWOF
#undef KLOF
}

// ---- final: out[b] = sum_n s(core[b,n]) * Wout[n] + bout -----------------
__global__ __launch_bounds__(256) void final_reduce(
    const f16* __restrict__ core, const float* __restrict__ Wout,
    const float* __restrict__ bout, const float* __restrict__ weight,
    const float* __restrict__ qbias, const float* __restrict__ qscale,
    const float* __restrict__ qshift, float* __restrict__ out) {
  const int b = blockIdx.x, t = threadIdx.x;
  const float sw = __sinf(weight[0]);
  const float qb = qbias[0], qs = qscale[0], qsh = qshift[0];
  f16x8 c8 = *reinterpret_cast<const f16x8*>(&core[(size_t)b * HID + t * 8]);
  float sum = 0.f;
#pragma unroll
  for (int j = 0; j < 8; ++j) {
    float c = (float)c8[j];
    float s = c + (sw * __sinf(c) + qb) * qs + qsh;
    sum += s * Wout[t * 8 + j];
  }
#pragma unroll
  for (int off = 32; off >= 1; off >>= 1) sum += __shfl_down(sum, off, 64);
  __shared__ float red[4];
  if ((t & 63) == 0) red[t >> 6] = sum;
  __syncthreads();
  if (t == 0) out[b] = red[0] + red[1] + red[2] + red[3] + bout[0];
}

extern "C" void kernel_launch(void* const* d_in, const int* in_sizes, int n_in,
                              void* d_out, int out_size, void* d_ws, size_t ws_size,
                              hipStream_t stream) {
  const float* x    = (const float*)d_in[0];
  const float* W1   = (const float*)d_in[1];
  const float* b1   = (const float*)d_in[2];
  const float* W2   = (const float*)d_in[3];
  const float* b2   = (const float*)d_in[4];
  const float* W3   = (const float*)d_in[5];
  const float* b3   = (const float*)d_in[6];
  const float* Wout = (const float*)d_in[7];
  const float* bout = (const float*)d_in[8];
  const float* wgt  = (const float*)d_in[9];
  const float* qb   = (const float*)d_in[10];
  const float* qs   = (const float*)d_in[11];
  const float* qsh  = (const float*)d_in[12];
  float* out = (float*)d_out;

  char* ws = (char*)d_ws;
  size_t off = 0;
  f16* xh  = (f16*)(ws + off); off += (size_t)BATCH * IN_DIM * sizeof(f16);
  f16* w1t = (f16*)(ws + off); off += (size_t)HID * IN_DIM * sizeof(f16);
  f16* w2t = (f16*)(ws + off); off += (size_t)HID * HID * sizeof(f16);
  f16* w3t = (f16*)(ws + off); off += (size_t)HID * HID * sizeof(f16);
  f16* h1  = (f16*)(ws + off); off += (size_t)BATCH * HID * sizeof(f16);
  f16* h2  = (f16*)(ws + off); off += (size_t)BATCH * HID * sizeof(f16);

  {
    int n4 = BATCH * IN_DIM / 4;
    cast_kernel<<<(n4 + 255) / 256, 256, 0, stream>>>(x, xh, n4);
  }
  {
    dim3 blk(32, 8);
    transpose_cast3<<<10240, blk, 0, stream>>>(W1, W2, W3, w1t, w2t, w3t);
  }
  const int grid = (BATCH / 256) * (HID / 256);  // 256 blocks = 1/CU
  gemm256_bias_tanh<IN_DIM><<<grid, 512, 0, stream>>>(xh, w1t, b1, h1);
  gemm256_bias_tanh<HID>   <<<grid, 512, 0, stream>>>(h1, w2t, b2, h2);
  gemm256_bias_tanh<HID>   <<<grid, 512, 0, stream>>>(h2, w3t, b3, h1);
  final_reduce<<<BATCH, 256, 0, stream>>>(h1, Wout, bout, wgt, qb, qs, qsh, out);
}